// Round 1
// 1608.143 us; speedup vs baseline: 1.0007x; 1.0007x over previous
//
#include <hip/hip_runtime.h>
#include <hip/hip_bf16.h>
#include <cstdint>
#include <cstddef>

// ---------------- problem constants ----------------
#define BB 8
#define NN 8192
#define MM 1024
#define SS 32
#define PTOT (BB*MM*SS)          // 262144
// threshold must match f32(0.2*0.2 computed in double) — NOT 0.2f*0.2f
__device__ __constant__ float kR2 = 0.039999999105930328f;

// ---------------- stats layout (float offsets in ws) ----------------
#define ST_SUM0L 0
#define ST_SQ0L  64
#define ST_SUM0F 128
#define ST_SQ0F  192
#define ST_SUM1  256
#define ST_SQ1   320
#define ST_SUM2  384
#define ST_SQ2   512
#define P_AL     640
#define P_BL     704
#define P_AF     768
#define P_BF     832
#define P_A1     896
#define P_B1     960
#define P_A2     1024
#define P_B2     1152
#define STATS_ZERO_BYTES (640*4)

// ws byte offsets
#define OFF_FPS   0u
#define OFF_STATS 32768u
#define OFF_X0    40960u
#define OFF_Z1    12623872u      // x0 ends at 40960 + 262144*48 = 12623872

// ==================================================================
// 1) FPS v4: 1 block/batch, 512 threads (8 waves), 16 pts/thread held in
//    NAMED scalar registers. CRITICAL: __launch_bounds__(512, 2) — we only
//    ever launch 8 blocks (1/CU = 2 waves/SIMD), so allow up to 256
//    VGPR/wave. Without the ",2" the backend's occupancy heuristic capped
//    the kernel at 56 VGPRs and rematerialized the 48 coordinate values
//    from global memory EVERY iteration (the 1178us / VGPR=56 symptom).
//    (val, ~idx) packed in a u64 key: unsigned max == argmax w/ lowest-index
//    tie-break (np.argmax semantics). One barrier/iter via double-buffered
//    wave partials.
// ==================================================================
#define FPS_DECL(k) float px##k, py##k, pz##k, tmp##k;
#define FPS_INIT(k) { const int p = ((k) << 9) | t;            \
    px##k = cb[p * 3 + 0]; py##k = cb[p * 3 + 1];              \
    pz##k = cb[p * 3 + 2]; tmp##k = 1e10f; }
#define FPS_UPD(k) {                                           \
    const float dx = px##k - cx, dy = py##k - cy, dz = pz##k - cz; \
    float d;                                                   \
    { _Pragma("clang fp contract(off)")                        \
      d = dx * dx; d = d + dy * dy; d = d + dz * dz; }         \
    tmp##k = fminf(tmp##k, d); }
#define FPS_SEL(k) if (tmp##k == lmax) lidx = ((k) << 9) | t;

__global__ __launch_bounds__(512, 2) void fps_kernel(const float* __restrict__ center,
                                                     int* __restrict__ fps_idx) {
  const int b = blockIdx.x;
  const int t = threadIdx.x;               // 0..511
  const int lane = t & 63, wid = t >> 6;   // 8 waves
  const float* cb = center + (size_t)b * NN * 3;
  FPS_DECL(0) FPS_DECL(1) FPS_DECL(2) FPS_DECL(3)
  FPS_DECL(4) FPS_DECL(5) FPS_DECL(6) FPS_DECL(7)
  FPS_DECL(8) FPS_DECL(9) FPS_DECL(10) FPS_DECL(11)
  FPS_DECL(12) FPS_DECL(13) FPS_DECL(14) FPS_DECL(15)
  FPS_INIT(0) FPS_INIT(1) FPS_INIT(2) FPS_INIT(3)
  FPS_INIT(4) FPS_INIT(5) FPS_INIT(6) FPS_INIT(7)
  FPS_INIT(8) FPS_INIT(9) FPS_INIT(10) FPS_INIT(11)
  FPS_INIT(12) FPS_INIT(13) FPS_INIT(14) FPS_INIT(15)
  __shared__ unsigned long long s_wkey[2][8];
  int far = 0;
  for (int i = 0; i < MM; ++i) {
    if (t == 0) fps_idx[(b << 10) + i] = far;
    // centroid via uniform (scalar-path) load; far is block-uniform
    const int fs = __builtin_amdgcn_readfirstlane(far);
    const float cx = cb[fs * 3 + 0];
    const float cy = cb[fs * 3 + 1];
    const float cz = cb[fs * 3 + 2];
    FPS_UPD(0) FPS_UPD(1) FPS_UPD(2) FPS_UPD(3)
    FPS_UPD(4) FPS_UPD(5) FPS_UPD(6) FPS_UPD(7)
    FPS_UPD(8) FPS_UPD(9) FPS_UPD(10) FPS_UPD(11)
    FPS_UPD(12) FPS_UPD(13) FPS_UPD(14) FPS_UPD(15)
    // tree-max of the 16 temps
    const float a0 = fmaxf(tmp0, tmp1),  a1 = fmaxf(tmp2, tmp3);
    const float a2 = fmaxf(tmp4, tmp5),  a3 = fmaxf(tmp6, tmp7);
    const float a4 = fmaxf(tmp8, tmp9),  a5 = fmaxf(tmp10, tmp11);
    const float a6 = fmaxf(tmp12, tmp13), a7 = fmaxf(tmp14, tmp15);
    const float b0 = fmaxf(a0, a1), b1 = fmaxf(a2, a3);
    const float b2 = fmaxf(a4, a5), b3 = fmaxf(a6, a7);
    const float c0 = fmaxf(b0, b1), c1 = fmaxf(b2, b3);
    const float lmax = fmaxf(c0, c1);
    // lowest global index among ties (descending k: lowest k wins last)
    int lidx = 0x7fffffff;
    FPS_SEL(15) FPS_SEL(14) FPS_SEL(13) FPS_SEL(12)
    FPS_SEL(11) FPS_SEL(10) FPS_SEL(9)  FPS_SEL(8)
    FPS_SEL(7)  FPS_SEL(6)  FPS_SEL(5)  FPS_SEL(4)
    FPS_SEL(3)  FPS_SEL(2)  FPS_SEL(1)  FPS_SEL(0)
    // pack: non-negative float bits are order-preserving; ~idx breaks ties low
    unsigned long long key =
        ((unsigned long long)__float_as_uint(lmax) << 32) | (unsigned)(~lidx);
    for (int off = 1; off < 64; off <<= 1) {
      const unsigned long long ok = __shfl_xor(key, off);
      key = (ok > key) ? ok : key;
    }
    if (lane == 0) s_wkey[i & 1][wid] = key;
    __syncthreads();
    const unsigned long long* sk = s_wkey[i & 1];
    unsigned long long best = sk[0];
#pragma unroll
    for (int w = 1; w < 8; ++w) { const unsigned long long o = sk[w]; best = (o > best) ? o : best; }
    far = (int)(~(unsigned)best);
  }
}

// ==================================================================
// 2) Ball query (first 32 smallest in-radius indices) + gather + concat
//    one wave per (b,m); also writes new_center/new_normal outputs
// ==================================================================
__global__ __launch_bounds__(256) void ball_gather_kernel(
    const float* __restrict__ center, const float* __restrict__ normal,
    const float* __restrict__ feature, const int* __restrict__ fps_idx,
    float* __restrict__ x0, float* __restrict__ out) {
  const int lane = threadIdx.x & 63;
  const int wq = (int)((blockIdx.x * blockDim.x + threadIdx.x) >> 6); // 0..8191
  const int b = wq >> 10, m = wq & 1023;
  const float* cb = center  + (size_t)b * NN * 3;
  const float* nb = normal  + (size_t)b * NN * 3;
  const float* fb = feature + (size_t)b * 6 * NN;
  const int pstar = fps_idx[(b << 10) + m];
  const float qx = cb[pstar * 3 + 0], qy = cb[pstar * 3 + 1], qz = cb[pstar * 3 + 2];
  if (lane < 3) {
    out[b * 3072 + lane * 1024 + m]         = cb[pstar * 3 + lane];   // new_center^T
    out[24576 + b * 3072 + lane * 1024 + m] = nb[pstar * 3 + lane];   // new_normal^T
  }
  const size_t pos_base = (size_t)((b << 10) + m) * SS;
  int total = 0;
  int first_p = -1;
  const float r2 = kR2;
  for (int base = 0; base < NN && total < SS; base += 64) {
    const int p = base + lane;
    const float ppx = cb[p * 3], ppy = cb[p * 3 + 1], ppz = cb[p * 3 + 2];
    const float dx = ppx - qx, dy = ppy - qy, dz = ppz - qz;
    float d2;
    {
#pragma clang fp contract(off)
      d2 = dx * dx;
      d2 = d2 + dy * dy;
      d2 = d2 + dz * dz;
    }
    const bool hit = d2 < r2;
    const unsigned long long msk = __ballot(hit);
    if (first_p < 0 && msk) first_p = base + (int)__builtin_ctzll(msk);
    const int rank = (int)__popcll(msk & ((1ull << lane) - 1ull));
    const int slot = total + rank;
    if (hit && slot < SS) {
      float4 v0, v1, v2;
      v0.x = dx; v0.y = dy; v0.z = dz;             // group_center - new_center
      v0.w = nb[p * 3 + 0];
      v1.x = nb[p * 3 + 1];
      v1.y = nb[p * 3 + 2];
      v1.z = fb[p];
      v1.w = fb[NN + p];
      v2.x = fb[2 * NN + p];
      v2.y = fb[3 * NN + p];
      v2.z = fb[4 * NN + p];
      v2.w = fb[5 * NN + p];
      float4* dst = (float4*)(x0 + (pos_base + (size_t)slot) * 12);
      dst[0] = v0; dst[1] = v1; dst[2] = v2;
    }
    total += (int)__popcll(msk);
  }
  if (total < SS) {                                // pad with first hit (ref semantics)
    if (first_p < 0) first_p = 0;
    const int p = first_p;
    const float ppx = cb[p * 3], ppy = cb[p * 3 + 1], ppz = cb[p * 3 + 2];
    float4 v0, v1, v2;
    v0.x = ppx - qx; v0.y = ppy - qy; v0.z = ppz - qz;
    v0.w = nb[p * 3 + 0]; v1.x = nb[p * 3 + 1]; v1.y = nb[p * 3 + 2];
    v1.z = fb[p]; v1.w = fb[NN + p];
    v2.x = fb[2 * NN + p]; v2.y = fb[3 * NN + p]; v2.z = fb[4 * NN + p]; v2.w = fb[5 * NN + p];
    for (int slot = total + lane; slot < SS; slot += 64) {
      float4* dst = (float4*)(x0 + (pos_base + (size_t)slot) * 12);
      dst[0] = v0; dst[1] = v1; dst[2] = v2;
    }
  }
}

// ==================================================================
// 3) stats for layer0 conv outputs (loc 64ch + ftr 64ch), lane = channel
// ==================================================================
__global__ __launch_bounds__(256) void stats0_kernel(
    const float* __restrict__ x0,
    const float* __restrict__ w_l0, const float* __restrict__ b_l0,
    const float* __restrict__ w_f0, const float* __restrict__ b_f0,
    float* __restrict__ stats) {
  const int lane = threadIdx.x & 63, wid = threadIdx.x >> 6;
  const int wgid = blockIdx.x * 4 + wid;           // 0..2047
  float wl[3], wf[9];
#pragma unroll
  for (int j = 0; j < 3; ++j) wl[j] = w_l0[lane * 3 + j];
#pragma unroll
  for (int j = 0; j < 9; ++j) wf[j] = w_f0[lane * 9 + j];
  const float bl = b_l0[lane], bf = b_f0[lane];
  float sL = 0.f, qL = 0.f, sF = 0.f, qF = 0.f;
  for (int it = 0; it < 128; ++it) {
    const int p = it * 2048 + wgid;
    const float4* row = (const float4*)(x0 + (size_t)p * 12);
    const float4 r0 = row[0], r1 = row[1], r2 = row[2];
    const float yL = bl + wl[0] * r0.x + wl[1] * r0.y + wl[2] * r0.z;
    const float yF = bf + wf[0] * r0.w + wf[1] * r1.x + wf[2] * r1.y + wf[3] * r1.z +
                     wf[4] * r1.w + wf[5] * r2.x + wf[6] * r2.y + wf[7] * r2.z + wf[8] * r2.w;
    sL += yL; qL += yL * yL; sF += yF; qF += yF * yF;
  }
  __shared__ float red[4][64][4];
  red[wid][lane][0] = sL; red[wid][lane][1] = qL;
  red[wid][lane][2] = sF; red[wid][lane][3] = qF;
  __syncthreads();
  if (wid == 0) {
    float a0 = 0.f, a1 = 0.f, a2 = 0.f, a3 = 0.f;
    for (int w = 0; w < 4; ++w) {
      a0 += red[w][lane][0]; a1 += red[w][lane][1];
      a2 += red[w][lane][2]; a3 += red[w][lane][3];
    }
    atomicAdd(&stats[ST_SUM0L + lane], a0);
    atomicAdd(&stats[ST_SQ0L + lane], a1);
    atomicAdd(&stats[ST_SUM0F + lane], a2);
    atomicAdd(&stats[ST_SQ0F + lane], a3);
  }
}

// ==================================================================
// finalize kernels: sums -> (a, b') with y_norm = a*y + b'
// ==================================================================
__global__ void finalize0_kernel(float* stats, const float* gl, const float* bel,
                                 const float* gf, const float* bef) {
  const int t = threadIdx.x;                        // 128
  const float invN = 1.0f / (float)PTOT;
  if (t < 64) {
    const float mean = stats[ST_SUM0L + t] * invN;
    const float var  = stats[ST_SQ0L + t] * invN - mean * mean;
    const float a = gl[t] / sqrtf(var + 1e-5f);
    stats[P_AL + t] = a;
    stats[P_BL + t] = bel[t] - a * mean;
  } else {
    const int c = t - 64;
    const float mean = stats[ST_SUM0F + c] * invN;
    const float var  = stats[ST_SQ0F + c] * invN - mean * mean;
    const float a = gf[c] / sqrtf(var + 1e-5f);
    stats[P_AF + c] = a;
    stats[P_BF + c] = bef[c] - a * mean;
  }
}
__global__ void finalize1_kernel(float* stats, const float* g, const float* be) {
  const int t = threadIdx.x;                        // 64
  const float invN = 1.0f / (float)PTOT;
  const float mean = stats[ST_SUM1 + t] * invN;
  const float var  = stats[ST_SQ1 + t] * invN - mean * mean;
  const float a = g[t] / sqrtf(var + 1e-5f);
  stats[P_A1 + t] = a;
  stats[P_B1 + t] = be[t] - a * mean;
}
__global__ void finalize2_kernel(float* stats, const float* g, const float* be) {
  const int t = threadIdx.x;                        // 128
  const float invN = 1.0f / (float)PTOT;
  const float mean = stats[ST_SUM2 + t] * invN;
  const float var  = stats[ST_SQ2 + t] * invN - mean * mean;
  const float a = g[t] / sqrtf(var + 1e-5f);
  stats[P_A2 + t] = a;
  stats[P_B2 + t] = be[t] - a * mean;
}

// ==================================================================
// 5) conv0 + BN0 + relu  ->  conv1 (z1 stored f32) + stats1
//    lane = output channel; per-position x1 broadcast via wave-private LDS
// ==================================================================
__global__ __launch_bounds__(256) void k5_kernel(
    const float* __restrict__ x0, float* __restrict__ z1,
    float* __restrict__ stats,
    const float* __restrict__ w_l0, const float* __restrict__ b_l0,
    const float* __restrict__ w_f0, const float* __restrict__ b_f0,
    const float* __restrict__ w1, const float* __restrict__ b1) {
  const int lane = threadIdx.x & 63, wid = threadIdx.x >> 6;
  const int wgid = blockIdx.x * 4 + wid;
  float wl[3], wf[9], w1r[64];
#pragma unroll
  for (int j = 0; j < 3; ++j) wl[j] = w_l0[lane * 3 + j];
#pragma unroll
  for (int j = 0; j < 9; ++j) wf[j] = w_f0[lane * 9 + j];
#pragma unroll
  for (int k = 0; k < 64; ++k) w1r[k] = w1[lane * 64 + k];
  const float bl = b_l0[lane], bf = b_f0[lane], b1v = b1[lane];
  const float aL = stats[P_AL + lane], bL = stats[P_BL + lane];
  const float aF = stats[P_AF + lane], bF = stats[P_BF + lane];
  float s1 = 0.f, q1 = 0.f;
  __shared__ __align__(16) float sx[2][4][64];
  for (int it = 0; it < 128; ++it) {
    const int p = it * 2048 + wgid;
    const float4* row = (const float4*)(x0 + (size_t)p * 12);
    const float4 r0 = row[0], r1 = row[1], r2 = row[2];
    const float yL = bl + wl[0] * r0.x + wl[1] * r0.y + wl[2] * r0.z;
    const float yF = bf + wf[0] * r0.w + wf[1] * r1.x + wf[2] * r1.y + wf[3] * r1.z +
                     wf[4] * r1.w + wf[5] * r2.x + wf[6] * r2.y + wf[7] * r2.z + wf[8] * r2.w;
    const float x1 = fmaxf(aL * yL + bL + (aF * yF + bF), 0.f);
    sx[it & 1][wid][lane] = x1;
    __syncthreads();
    float acc = b1v;
    const float4* xv = (const float4*)&sx[it & 1][wid][0];
#pragma unroll
    for (int k4 = 0; k4 < 16; ++k4) {
      const float4 xq = xv[k4];
      acc += w1r[4 * k4 + 0] * xq.x + w1r[4 * k4 + 1] * xq.y +
             w1r[4 * k4 + 2] * xq.z + w1r[4 * k4 + 3] * xq.w;
    }
    s1 += acc; q1 += acc * acc;
    z1[(size_t)p * 64 + lane] = acc;
  }
  __shared__ float red[4][64][2];
  red[wid][lane][0] = s1; red[wid][lane][1] = q1;
  __syncthreads();
  if (wid == 0) {
    float a0 = 0.f, a1v = 0.f;
    for (int w = 0; w < 4; ++w) { a0 += red[w][lane][0]; a1v += red[w][lane][1]; }
    atomicAdd(&stats[ST_SUM1 + lane], a0);
    atomicAdd(&stats[ST_SQ1 + lane], a1v);
  }
}

// ==================================================================
// 6) BN1+relu -> conv2 (128ch) + stats2; z2 written bf16 IN-PLACE over z1
// ==================================================================
__global__ __launch_bounds__(256, 2) void k6_kernel(
    float* __restrict__ z12, float* __restrict__ stats,
    const float* __restrict__ w2, const float* __restrict__ b2) {
  const int lane = threadIdx.x & 63, wid = threadIdx.x >> 6;
  const int wgid = blockIdx.x * 4 + wid;
  float w2a[64], w2b[64];
#pragma unroll
  for (int k = 0; k < 64; ++k) w2a[k] = w2[lane * 64 + k];
#pragma unroll
  for (int k = 0; k < 64; ++k) w2b[k] = w2[(lane + 64) * 64 + k];
  const float b2a = b2[lane], b2b = b2[lane + 64];
  const float a1 = stats[P_A1 + lane], b1p = stats[P_B1 + lane];
  float s0 = 0.f, q0 = 0.f, s1 = 0.f, q1 = 0.f;
  __shared__ __align__(16) float sx[2][4][64];
  __hip_bfloat16* zo = (__hip_bfloat16*)z12;
  for (int it = 0; it < 128; ++it) {
    const int p = it * 2048 + wgid;
    const float z = z12[(size_t)p * 64 + lane];
    const float x2 = fmaxf(a1 * z + b1p, 0.f);
    sx[it & 1][wid][lane] = x2;
    __syncthreads();
    float acc0 = b2a, acc1 = b2b;
    const float4* xv = (const float4*)&sx[it & 1][wid][0];
#pragma unroll
    for (int k4 = 0; k4 < 16; ++k4) {
      const float4 xq = xv[k4];
      acc0 += w2a[4 * k4] * xq.x + w2a[4 * k4 + 1] * xq.y + w2a[4 * k4 + 2] * xq.z + w2a[4 * k4 + 3] * xq.w;
      acc1 += w2b[4 * k4] * xq.x + w2b[4 * k4 + 1] * xq.y + w2b[4 * k4 + 2] * xq.z + w2b[4 * k4 + 3] * xq.w;
    }
    s0 += acc0; q0 += acc0 * acc0; s1 += acc1; q1 += acc1 * acc1;
    zo[(size_t)p * 128 + lane]      = __float2bfloat16(acc0);
    zo[(size_t)p * 128 + 64 + lane] = __float2bfloat16(acc1);
  }
  __shared__ float red[4][64][4];
  red[wid][lane][0] = s0; red[wid][lane][1] = q0;
  red[wid][lane][2] = s1; red[wid][lane][3] = q1;
  __syncthreads();
  if (wid == 0) {
    float t0 = 0.f, t1 = 0.f, t2 = 0.f, t3 = 0.f;
    for (int w = 0; w < 4; ++w) {
      t0 += red[w][lane][0]; t1 += red[w][lane][1];
      t2 += red[w][lane][2]; t3 += red[w][lane][3];
    }
    atomicAdd(&stats[ST_SUM2 + lane], t0);
    atomicAdd(&stats[ST_SQ2 + lane], t1);
    atomicAdd(&stats[ST_SUM2 + 64 + lane], t2);
    atomicAdd(&stats[ST_SQ2 + 64 + lane], t3);
  }
}

// ==================================================================
// 7) BN2 + relu + max over nsample, transposed write via LDS tile
//    block = (b, 64-m tile); out x shape (8,128,1024)
// ==================================================================
__global__ __launch_bounds__(256) void k7_kernel(const __hip_bfloat16* __restrict__ z2,
                                                 const float* __restrict__ stats,
                                                 float* __restrict__ out3) {
  const int b = blockIdx.x >> 4;
  const int mt = blockIdx.x & 15;
  const int t = threadIdx.x;
  const int o = t & 127, h = t >> 7;
  const float a = stats[P_A2 + o], bb = stats[P_B2 + o];
  __shared__ float tile[128][65];
  for (int j = 0; j < 32; ++j) {
    const int ml = h + 2 * j;
    const size_t rowbase = ((size_t)(b * 1024 + mt * 64 + ml)) * SS;
    float acc = -1e30f;
    for (int s = 0; s < SS; ++s) {
      const float v = __bfloat162float(z2[(rowbase + s) * 128 + o]);
      acc = fmaxf(acc, a * v + bb);
    }
    tile[o][ml] = fmaxf(acc, 0.f);                 // relu after max (monotone)
  }
  __syncthreads();
  const int r = t >> 1, c0 = (t & 1) * 32;
  float* dst = out3 + (size_t)b * 128 * 1024 + (size_t)r * 1024 + mt * 64 + c0;
  for (int j = 0; j < 32; ++j) dst[j] = tile[r][c0 + j];
}

// ==================================================================
extern "C" void kernel_launch(void* const* d_in, const int* in_sizes, int n_in,
                              void* d_out, int out_size, void* d_ws, size_t ws_size,
                              hipStream_t stream) {
  const float* center  = (const float*)d_in[0];
  const float* normal  = (const float*)d_in[1];
  const float* feature = (const float*)d_in[2];
  const float* w_l0 = (const float*)d_in[3];
  const float* b_l0 = (const float*)d_in[4];
  const float* g_l0 = (const float*)d_in[5];
  const float* be_l0 = (const float*)d_in[6];
  const float* w_f0 = (const float*)d_in[7];
  const float* b_f0 = (const float*)d_in[8];
  const float* g_f0 = (const float*)d_in[9];
  const float* be_f0 = (const float*)d_in[10];
  const float* w1 = (const float*)d_in[11];
  const float* b1 = (const float*)d_in[12];
  const float* g1 = (const float*)d_in[13];
  const float* be1 = (const float*)d_in[14];
  const float* w2 = (const float*)d_in[15];
  const float* b2 = (const float*)d_in[16];
  const float* g2 = (const float*)d_in[17];
  const float* be2 = (const float*)d_in[18];
  float* out = (float*)d_out;
  char* ws = (char*)d_ws;
  int*   fps_idx = (int*)(ws + OFF_FPS);
  float* stats   = (float*)(ws + OFF_STATS);
  float* x0      = (float*)(ws + OFF_X0);
  float* z1      = (float*)(ws + OFF_Z1);

  hipMemsetAsync(stats, 0, STATS_ZERO_BYTES, stream);
  hipLaunchKernelGGL(fps_kernel, dim3(8), dim3(512), 0, stream, center, fps_idx);
  hipLaunchKernelGGL(ball_gather_kernel, dim3(2048), dim3(256), 0, stream,
                     center, normal, feature, fps_idx, x0, out);
  hipLaunchKernelGGL(stats0_kernel, dim3(512), dim3(256), 0, stream,
                     x0, w_l0, b_l0, w_f0, b_f0, stats);
  hipLaunchKernelGGL(finalize0_kernel, dim3(1), dim3(128), 0, stream,
                     stats, g_l0, be_l0, g_f0, be_f0);
  hipLaunchKernelGGL(k5_kernel, dim3(512), dim3(256), 0, stream,
                     x0, z1, stats, w_l0, b_l0, w_f0, b_f0, w1, b1);
  hipLaunchKernelGGL(finalize1_kernel, dim3(1), dim3(64), 0, stream, stats, g1, be1);
  hipLaunchKernelGGL(k6_kernel, dim3(512), dim3(256), 0, stream, z1, stats, w2, b2);
  hipLaunchKernelGGL(finalize2_kernel, dim3(1), dim3(128), 0, stream, stats, g2, be2);
  hipLaunchKernelGGL(k7_kernel, dim3(128), dim3(256), 0, stream,
                     (const __hip_bfloat16*)z1, stats, out + 49152);
}